// Round 2
// baseline (300.836 us; speedup 1.0000x reference)
//
#include <hip/hip_runtime.h>
#include <hip/hip_bf16.h>
#include <math.h>

#define M_  8
#define N_  1024
#define D_  512
#define H_  512
#define PI_ 3.14159265358979323846f

// ---------------- ws layout (in floats) — total ~0.82M floats (~3.3 MB) ----------------
static const size_t OFF_ABS = 0;                            // 8192
static const size_t OFF_SIG = OFF_ABS + 8192;               // 1 (pad 64)
static const size_t OFF_PA  = OFF_SIG + 64;                 // 8*64*512
static const size_t OFF_PZR = OFF_PA  + (size_t)M_*64*D_;
static const size_t OFF_PZI = OFF_PZR + (size_t)M_*64*D_;
static const size_t OFF_MO  = OFF_PZI + (size_t)M_*64*D_;   // 8*512
static const size_t OFF_COH = OFF_MO  + (size_t)M_*D_;      // 8 (pad 64)
static const size_t OFF_GX  = OFF_COH + 64;                 // 8*1536
static const size_t OFF_GH  = OFF_GX  + (size_t)M_*3*H_;
static const size_t OFF_H   = OFF_GH  + (size_t)M_*3*H_;    // 8*512
static const size_t OFF_Q   = OFF_H   + (size_t)M_*H_;
static const size_t OFF_K   = OFF_Q   + (size_t)M_*H_;
static const size_t OFF_V   = OFF_K   + (size_t)M_*H_;
static const size_t OFF_ATT = OFF_V   + (size_t)M_*H_;      // 512

// ---------------- kernels ----------------

__global__ void sig_kernel(const float* __restrict__ x, float* __restrict__ sigmax) {
    __shared__ float red[D_];
    int t = threadIdx.x;
    red[t] = fabsf(x[t]);
    __syncthreads();
    for (int s = D_/2; s > 0; s >>= 1) {
        if (t < s) red[t] = fmaxf(red[t], red[t + s]);
        __syncthreads();
    }
    if (t == 0) *sigmax = red[0];
}

// one wave per cell: absum[cell] = sum_j amp0[cell][j]
__global__ void absum_kernel(const float* __restrict__ amp0, float* __restrict__ absum) {
    const int cell = blockIdx.x;           // m*N_ + i, 8192 total
    const int lane = threadIdx.x;          // 0..63
    const size_t base = (size_t)cell * D_;
    float acc = 0.f;
    for (int kk = 0; kk < 8; ++kk) acc += amp0[base + kk * 64 + lane];
    for (int off = 32; off > 0; off >>= 1) acc += __shfl_down(acc, off);
    if (lane == 0) absum[cell] = acc;
}

// 512 blocks (8 m * 64 groups), 512 threads, 16 cells each; sincos computed on the fly
__global__ void micro_kernel(const float* __restrict__ amp0,
                             const float* __restrict__ phase0,
                             const float* __restrict__ pv,
                             const float* __restrict__ xsig,
                             const float* __restrict__ sigmax_p,
                             const int*   __restrict__ nbr_idx,
                             const float* __restrict__ nbr_mask,
                             const int*   __restrict__ step_p,
                             const float* __restrict__ absum,
                             float* __restrict__ pA,
                             float* __restrict__ pZr,
                             float* __restrict__ pZi,
                             int K) {
    const int m = blockIdx.x >> 6;
    const int g = blockIdx.x & 63;
    const int j = threadIdx.x;
    const float t  = 0.1f * (float)(*step_p);
    const float sm = *sigmax_p;
    const float pp = xsig[j] / (sm + 1e-8f) * (PI_ * 0.1f);

    const size_t mbase = (size_t)m * N_ * D_;
    float sumA = 0.f, sumZr = 0.f, sumZi = 0.f;
    __shared__ float red[D_];

    for (int ci = 0; ci < 16; ++ci) {
        const int i = g * 16 + ci;
        const size_t own = mbase + (size_t)i * D_ + j;
        const float a_i = amp0[own];
        const float th_i = phase0[own] + 0.1f * pv[own];
        float s_i, c_i;
        sincosf(th_i, &s_i, &c_i);
        const float st_re = a_i * c_i, st_im = a_i * s_i;

        float SA = 0.f, SB = 0.f, SC = 0.f, cnt = 0.f;
        float best = -1e30f; int midx = 0;
        for (int k = 0; k < K; ++k) {
            const int   nb = nbr_idx[i * K + k];
            const float w  = nbr_mask[i * K + k];
            if (w > 0.f) {
                const size_t nidx = mbase + (size_t)nb * D_ + j;
                const float an = amp0[nidx];
                const float thn = phase0[nidx] + 0.1f * pv[nidx];
                float sn, cn;
                sincosf(thn, &sn, &cn);
                const float ac = an * cn, as_ = an * sn;
                SA += ac * cn;  SB += ac * sn;  SC += as_ * sn;
                cnt += w;
                const float sc = absum[m * N_ + nb];
                if (sc > best) { best = sc; midx = nb; }   // first-max (strict >)
            }
        }
        if (cnt < 1.f) cnt = 1.f;
        const float f = 0.03f / cnt;   // 0.3 * 0.1 / cnt
        float nre = 0.7f * st_re + f * (c_i * SA + s_i * SB);
        float nim = 0.7f * st_im + f * (c_i * SB + s_i * SC);

        // morph = new * conj(src) / |new|
        const size_t sidx = mbase + (size_t)midx * D_ + j;
        const float sa = amp0[sidx];
        const float ths = phase0[sidx] + 0.1f * pv[sidx];
        float ssn, scc;
        sincosf(ths, &ssn, &scc);
        const float src_re = sa * scc, src_im = sa * ssn;
        const float nmag = sqrtf(nre * nre + nim * nim);
        const float inv = 1.f / nmag;
        const float mre = (nre * src_re + nim * src_im) * inv;
        const float mim = (nim * src_re - nre * src_im) * inv;
        nre += 0.02f * mre;
        nim += 0.02f * mim;

        // global wave (positive factor: angle unchanged)
        const float wfac = 1.f + 0.02f * sinf(t + 2.f * PI_ * (float)i / (float)N_);
        nre *= wfac; nim *= wfac;

        const float ampn = sqrtf(nre * nre + nim * nim);

        // row max over j
        red[j] = ampn;
        __syncthreads();
        for (int ss2 = D_/2; ss2 > 0; ss2 >>= 1) {
            if (j < ss2) red[j] = fmaxf(red[j], red[j + ss2]);
            __syncthreads();
        }
        const float rmax = red[0];
        __syncthreads();

        const float anorm   = ampn / (rmax + 1e-8f);
        const float scale_i = 0.1f / (1.f + 0.1f * (float)i);
        const float ang     = atan2f(nim, nre) + pp * scale_i;
        float ui, ur;
        sincosf(ang, &ui, &ur);
        sumA  += anorm;
        sumZr += ur;
        sumZi += ui;
    }
    const size_t pidx = ((size_t)m * 64 + g) * D_ + j;
    pA[pidx]  = sumA;
    pZr[pidx] = sumZr;
    pZi[pidx] = sumZi;
}

__global__ void reduce_kernel(const float* __restrict__ pA,
                              const float* __restrict__ pZr,
                              const float* __restrict__ pZi,
                              float* __restrict__ micro_out,
                              float* __restrict__ coh) {
    const int m = blockIdx.x, j = threadIdx.x;
    float sa = 0.f, zr = 0.f, zi = 0.f;
    for (int g = 0; g < 64; ++g) {
        const size_t idx = ((size_t)m * 64 + g) * D_ + j;
        sa += pA[idx]; zr += pZr[idx]; zi += pZi[idx];
    }
    micro_out[m * D_ + j] = sa * (1.f / (float)N_);
    const float mag = sqrtf(zr * zr + zi * zi) * (1.f / (float)N_);
    __shared__ float red[D_];
    red[j] = mag;
    __syncthreads();
    for (int s = D_/2; s > 0; s >>= 1) {
        if (j < s) red[j] += red[j + s];
        __syncthreads();
    }
    if (j == 0) coh[m] = red[0] / (float)D_;
}

// gx[m][r] = micro_out[m]·w_ih[r] + b_ih[r];  gh[m][r] = h0[m]·w_hh[r] + b_hh[r]
// 768 blocks * 256 threads: first 384 blocks do w_ih, rest w_hh; 4 waves/block, wave=row
__global__ void gemm1_kernel(const float* __restrict__ micro_out,
                             const float* __restrict__ h0,
                             const float* __restrict__ w_ih, const float* __restrict__ b_ih,
                             const float* __restrict__ w_hh, const float* __restrict__ b_hh,
                             float* __restrict__ gx, float* __restrict__ gh) {
    __shared__ float vec[M_ * H_];
    const bool isX = blockIdx.x < 384;
    const float* v = isX ? micro_out : h0;
    for (int idx = threadIdx.x; idx < M_ * H_; idx += blockDim.x) vec[idx] = v[idx];
    __syncthreads();
    const int wave = threadIdx.x >> 6, lane = threadIdx.x & 63;
    const int r = ((isX ? blockIdx.x : blockIdx.x - 384) << 2) + wave;   // 0..1535
    const float* W = isX ? w_ih : w_hh;
    const float* B = isX ? b_ih : b_hh;
    float* G = isX ? gx : gh;
    float wv[8];
    for (int kk = 0; kk < 8; ++kk) wv[kk] = W[(size_t)r * H_ + kk * 64 + lane];
    for (int m = 0; m < M_; ++m) {
        float acc = 0.f;
        for (int kk = 0; kk < 8; ++kk) acc += wv[kk] * vec[m * H_ + kk * 64 + lane];
        for (int off = 32; off > 0; off >>= 1) acc += __shfl_down(acc, off);
        if (lane == 0) G[m * (3 * H_) + r] = acc + B[r];
    }
}

__global__ void gru_kernel(const float* __restrict__ gx, const float* __restrict__ gh,
                           const float* __restrict__ h0, float* __restrict__ h) {
    const int m = blockIdx.x, j = threadIdx.x;
    const float rx = gx[m*3*H_ + j],        rh = gh[m*3*H_ + j];
    const float zx = gx[m*3*H_ + H_ + j],   zh = gh[m*3*H_ + H_ + j];
    const float nx = gx[m*3*H_ + 2*H_ + j], nh = gh[m*3*H_ + 2*H_ + j];
    const float r  = 1.f / (1.f + expf(-(rx + rh)));
    const float z  = 1.f / (1.f + expf(-(zx + zh)));
    const float ng = tanhf(nx + r * nh);
    h[m * H_ + j] = (1.f - z) * ng + z * h0[m * H_ + j];
}

// 384 blocks * 256 threads, wave=row over {wq,wk,wv} x 512 rows
__global__ void qkv_kernel(const float* __restrict__ h,
                           const float* __restrict__ wq, const float* __restrict__ bq,
                           const float* __restrict__ wk, const float* __restrict__ bk,
                           const float* __restrict__ wv, const float* __restrict__ bv,
                           float* __restrict__ Q, float* __restrict__ Kk, float* __restrict__ V) {
    __shared__ float hv[M_ * H_];
    for (int idx = threadIdx.x; idx < M_ * H_; idx += blockDim.x) hv[idx] = h[idx];
    __syncthreads();
    const int gr = (blockIdx.x << 2) + (threadIdx.x >> 6);  // 0..1535
    const int lane = threadIdx.x & 63;
    const int which = gr / H_, r = gr % H_;
    const float* W = (which == 0) ? wq : ((which == 1) ? wk : wv);
    const float* B = (which == 0) ? bq : ((which == 1) ? bk : bv);
    float* O       = (which == 0) ? Q  : ((which == 1) ? Kk : V);
    float wvv[8];
    for (int kk = 0; kk < 8; ++kk) wvv[kk] = W[(size_t)r * H_ + kk * 64 + lane];
    for (int m = 0; m < M_; ++m) {
        float acc = 0.f;
        for (int kk = 0; kk < 8; ++kk) acc += wvv[kk] * hv[m * H_ + kk * 64 + lane];
        for (int off = 32; off > 0; off >>= 1) acc += __shfl_down(acc, off);
        if (lane == 0) O[m * H_ + r] = acc + B[r];
    }
}

__global__ void attn_kernel(const float* __restrict__ Q, const float* __restrict__ Kk,
                            const float* __restrict__ V, const float* __restrict__ coh,
                            float* __restrict__ attended) {
    __shared__ float sc[M_][M_];
    __shared__ float colw[M_];
    const int tid = threadIdx.x;
    const int a = tid >> 6, lane = tid & 63;
    for (int b = 0; b < M_; ++b) {
        float acc = 0.f;
        for (int kk = 0; kk < 8; ++kk) acc += Q[a * H_ + kk * 64 + lane] * Kk[b * H_ + kk * 64 + lane];
        for (int off = 32; off > 0; off >>= 1) acc += __shfl_down(acc, off);
        if (lane == 0) sc[a][b] = acc * rsqrtf((float)H_) * (0.5f + 0.5f * coh[a] * coh[b]);
    }
    __syncthreads();
    if (tid < M_) {
        float mx = -1e30f;
        for (int b = 0; b < M_; ++b) mx = fmaxf(mx, sc[tid][b]);
        float e[M_], sm = 0.f;
        for (int b = 0; b < M_; ++b) { e[b] = expf(sc[tid][b] - mx); sm += e[b]; }
        for (int b = 0; b < M_; ++b) sc[tid][b] = e[b] / sm;
    }
    __syncthreads();
    if (tid < M_) {
        float sum = 0.f;
        for (int a2 = 0; a2 < M_; ++a2) sum += sc[a2][tid];
        colw[tid] = sum * (1.f / (float)M_);
    }
    __syncthreads();
    float acc = 0.f;
    for (int b = 0; b < M_; ++b) acc += colw[b] * V[b * H_ + tid];
    attended[tid] = acc;
}

__global__ void faction_kernel(const float* __restrict__ h, const int* __restrict__ step_p,
                               float* __restrict__ out_tension) {
    const int j = threadIdx.x;
    const int step = *step_p;
    float h2[M_];
    for (int f = 0; f < 4; ++f) {
        const float a = h[(2*f) * H_ + j], b = h[(2*f+1) * H_ + j];
        const float mn = 0.5f * (a + b);
        h2[2*f]   = 0.85f * a + 0.15f * mn;
        h2[2*f+1] = 0.85f * b + 0.15f * mn;
    }
    if (step > 5) {
        float go = 0.f;
        for (int m = 0; m < M_; ++m) go += h2[m];
        go *= (1.f / (float)M_);
        for (int f = 0; f < 4; ++f) h2[2*f] = 0.85f * h2[2*f] + 0.15f * go;  // fs=2 -> dc=1 -> s=0 only
    }
    float sum = 0.f, sq = 0.f;
    for (int m = 0; m < M_; ++m) { sum += h2[m]; sq += h2[m] * h2[m]; }
    __shared__ float rs[D_], rq[D_];
    rs[j] = sum; rq[j] = sq;
    __syncthreads();
    for (int s = D_/2; s > 0; s >>= 1) {
        if (j < s) { rs[j] += rs[j + s]; rq[j] += rq[j + s]; }
        __syncthreads();
    }
    if (j == 0) {
        const float Nt = (float)(M_ * H_);
        const float mean = rs[0] / Nt;
        out_tension[0] = (rq[0] - Nt * mean * mean) / (Nt - 1.f);
    }
}

// 128 blocks * 256 threads, wave=output row
__global__ void pred_kernel(const float* __restrict__ attended,
                            const float* __restrict__ out_w, const float* __restrict__ out_b,
                            float* __restrict__ pred) {
    __shared__ float av[H_];
    for (int idx = threadIdx.x; idx < H_; idx += blockDim.x) av[idx] = attended[idx];
    __syncthreads();
    const int p = (blockIdx.x << 2) + (threadIdx.x >> 6);
    const int lane = threadIdx.x & 63;
    float acc = 0.f;
    for (int kk = 0; kk < 8; ++kk) acc += av[kk * 64 + lane] * out_w[(size_t)p * H_ + kk * 64 + lane];
    for (int off = 32; off > 0; off >>= 1) acc += __shfl_down(acc, off);
    if (lane == 0) pred[p] = acc + out_b[p];
}

// ---------------- launcher ----------------

extern "C" void kernel_launch(void* const* d_in, const int* in_sizes, int n_in,
                              void* d_out, int out_size, void* d_ws, size_t ws_size,
                              hipStream_t stream) {
    const float* x      = (const float*)d_in[0];
    const int*   step   = (const int*)  d_in[1];
    const float* amp0   = (const float*)d_in[2];
    const float* phase0 = (const float*)d_in[3];
    const float* pv     = (const float*)d_in[4];
    const int*   nbr_i  = (const int*)  d_in[5];
    const float* nbr_m  = (const float*)d_in[6];
    const float* h0     = (const float*)d_in[7];
    const float* w_ih   = (const float*)d_in[8];
    const float* b_ih   = (const float*)d_in[9];
    const float* w_hh   = (const float*)d_in[10];
    const float* b_hh   = (const float*)d_in[11];
    const float* wq     = (const float*)d_in[12];
    const float* bq     = (const float*)d_in[13];
    const float* wk     = (const float*)d_in[14];
    const float* bk     = (const float*)d_in[15];
    const float* wv     = (const float*)d_in[16];
    const float* bv     = (const float*)d_in[17];
    const float* out_w  = (const float*)d_in[18];
    const float* out_b  = (const float*)d_in[19];
    float* out = (float*)d_out;

    const int K = in_sizes[5] / N_;   // neighbor pad width (11)

    float* ws = (float*)d_ws;
    float* wABS = ws + OFF_ABS;
    float* wSIG = ws + OFF_SIG;
    float* wPA  = ws + OFF_PA;
    float* wPZR = ws + OFF_PZR;
    float* wPZI = ws + OFF_PZI;
    float* wMO  = ws + OFF_MO;
    float* wCOH = ws + OFF_COH;
    float* wGX  = ws + OFF_GX;
    float* wGH  = ws + OFF_GH;
    float* wH   = ws + OFF_H;
    float* wQ   = ws + OFF_Q;
    float* wK   = ws + OFF_K;
    float* wV   = ws + OFF_V;
    float* wATT = ws + OFF_ATT;

    sig_kernel<<<1, D_, 0, stream>>>(x, wSIG);
    absum_kernel<<<M_ * N_, 64, 0, stream>>>(amp0, wABS);
    micro_kernel<<<M_ * 64, D_, 0, stream>>>(amp0, phase0, pv, x, wSIG, nbr_i, nbr_m, step,
                                             wABS, wPA, wPZR, wPZI, K);
    reduce_kernel<<<M_, D_, 0, stream>>>(wPA, wPZR, wPZI, wMO, wCOH);
    gemm1_kernel<<<768, 256, 0, stream>>>(wMO, h0, w_ih, b_ih, w_hh, b_hh, wGX, wGH);
    gru_kernel<<<M_, D_, 0, stream>>>(wGX, wGH, h0, wH);
    qkv_kernel<<<384, 256, 0, stream>>>(wH, wq, bq, wk, bk, wv, bv, wQ, wK, wV);
    attn_kernel<<<1, D_, 0, stream>>>(wQ, wK, wV, wCOH, wATT);
    faction_kernel<<<1, D_, 0, stream>>>(wH, step, out + 512);
    pred_kernel<<<128, 256, 0, stream>>>(wATT, out_w, out_b, out);
}

// Round 3
// 226.992 us; speedup vs baseline: 1.3253x; 1.3253x over previous
//
#include <hip/hip_runtime.h>
#include <math.h>

#define M_  8
#define N_  1024
#define D_  512
#define H_  512
#define PI_ 3.14159265358979323846f

// ---------------- ws layout (in floats) — total ~3.2 MB (known-safe from R2) ----------------
static const size_t OFF_ABS = 0;                            // 8192
static const size_t OFF_SIG = OFF_ABS + 8192;               // 1 (pad 64)
static const size_t OFF_PA  = OFF_SIG + 64;                 // 8*64*512
static const size_t OFF_PZR = OFF_PA  + (size_t)M_*64*D_;
static const size_t OFF_PZI = OFF_PZR + (size_t)M_*64*D_;
static const size_t OFF_MO  = OFF_PZI + (size_t)M_*64*D_;   // 8*512
static const size_t OFF_COH = OFF_MO  + (size_t)M_*D_;      // 8 (pad 64)
static const size_t OFF_H   = OFF_COH + 64;                 // 8*512
static const size_t OFF_Q   = OFF_H   + (size_t)M_*H_;
static const size_t OFF_K   = OFF_Q   + (size_t)M_*H_;
static const size_t OFF_V   = OFF_K   + (size_t)M_*H_;
static const size_t OFF_ATT = OFF_V   + (size_t)M_*H_;      // 512

// load 8 consecutive floats starting at p[8*lane]
__device__ __forceinline__ void ld8(float* d, const float* __restrict__ p, int lane) {
    const float4* p4 = reinterpret_cast<const float4*>(p);
    float4 v0 = p4[2 * lane], v1 = p4[2 * lane + 1];
    d[0] = v0.x; d[1] = v0.y; d[2] = v0.z; d[3] = v0.w;
    d[4] = v1.x; d[5] = v1.y; d[6] = v1.z; d[7] = v1.w;
}

// ---------------- kernels ----------------

// blocks 0..8191: absum per cell; block 8192: sigmax. 64 threads each.
__global__ void prep_kernel(const float* __restrict__ amp0, const float* __restrict__ x,
                            float* __restrict__ absum, float* __restrict__ sigmax) {
    const int lane = threadIdx.x;
    if (blockIdx.x < M_ * N_) {
        float v[8];
        ld8(v, amp0 + (size_t)blockIdx.x * D_, lane);
        float acc = ((v[0] + v[1]) + (v[2] + v[3])) + ((v[4] + v[5]) + (v[6] + v[7]));
        for (int off = 32; off; off >>= 1) acc += __shfl_down(acc, off);
        if (lane == 0) absum[blockIdx.x] = acc;
    } else {
        float v[8];
        ld8(v, x, lane);
        float mx = 0.f;
        #pragma unroll
        for (int s = 0; s < 8; ++s) mx = fmaxf(mx, fabsf(v[s]));
        for (int off = 32; off; off >>= 1) mx = fmaxf(mx, __shfl_down(mx, off));
        if (lane == 0) *sigmax = mx;
    }
}

// 512 blocks x 512 thr. m = bid&7 (XCD pinning), g = bid>>3. Wave owns a cell (8 j per lane),
// 2 cells per wave. No per-cell barriers; hw trig; no atan2.
__global__ __launch_bounds__(512) void micro_kernel(
    const float* __restrict__ amp0, const float* __restrict__ phase0,
    const float* __restrict__ pv, const float* __restrict__ x,
    const float* __restrict__ sigmax_p, const int* __restrict__ nbr_idx,
    const float* __restrict__ nbr_mask, const int* __restrict__ step_p,
    const float* __restrict__ absum,
    float* __restrict__ pA, float* __restrict__ pZr, float* __restrict__ pZi, int K)
{
    const int m = blockIdx.x & 7;
    const int g = blockIdx.x >> 3;
    const int wid  = threadIdx.x >> 6;
    const int lane = threadIdx.x & 63;

    __shared__ float accA[D_], accZr[D_], accZi[D_];
    for (int idx = threadIdx.x; idx < D_; idx += 512) { accA[idx] = 0.f; accZr[idx] = 0.f; accZi[idx] = 0.f; }
    __syncthreads();

    const float t  = 0.1f * (float)(*step_p);
    const float sm = *sigmax_p;
    const int j0 = lane * 8;

    float pp[8];
    ld8(pp, x, lane);
    #pragma unroll
    for (int s = 0; s < 8; ++s) pp[s] = pp[s] / (sm + 1e-8f) * (PI_ * 0.1f);

    const size_t mrow = (size_t)m * N_;
    float sA[8], sZr[8], sZi[8];
    #pragma unroll
    for (int s = 0; s < 8; ++s) { sA[s] = 0.f; sZr[s] = 0.f; sZi[s] = 0.f; }

    for (int cc = 0; cc < 2; ++cc) {
        const int i = (g << 4) + (wid << 1) + cc;

        float SA[8], SB[8], SC[8];
        #pragma unroll
        for (int s = 0; s < 8; ++s) { SA[s] = 0.f; SB[s] = 0.f; SC[s] = 0.f; }
        float cnt = 0.f, best = -1e30f; int midx = 0;

        for (int k = 0; k < K; ++k) {
            const int   nb = nbr_idx[i * K + k];
            const float w  = nbr_mask[i * K + k];
            if (w > 0.f) {                           // wave-uniform branch
                const size_t noff = (mrow + nb) * (size_t)D_;
                float an[8], phn[8], pvn[8];
                ld8(an, amp0 + noff, lane);
                ld8(phn, phase0 + noff, lane);
                ld8(pvn, pv + noff, lane);
                #pragma unroll
                for (int s = 0; s < 8; ++s) {
                    const float th = fmaf(0.1f, pvn[s], phn[s]);
                    const float cn = __cosf(th), sn = __sinf(th);
                    const float ac = an[s] * cn, as_ = an[s] * sn;
                    SA[s] = fmaf(ac, cn, SA[s]);
                    SB[s] = fmaf(ac, sn, SB[s]);
                    SC[s] = fmaf(as_, sn, SC[s]);
                }
                cnt += w;
                const float sc = absum[mrow + nb];
                if (sc > best) { best = sc; midx = nb; }   // first-max (strict >)
            }
        }
        const float f = 0.03f / fmaxf(cnt, 1.f);   // 0.3 * 0.1 / cnt

        // own state + interference
        const size_t ooff = (mrow + i) * (size_t)D_;
        float a[8], ph[8], pw[8], nre[8], nim[8];
        ld8(a, amp0 + ooff, lane); ld8(ph, phase0 + ooff, lane); ld8(pw, pv + ooff, lane);
        #pragma unroll
        for (int s = 0; s < 8; ++s) {
            const float th = fmaf(0.1f, pw[s], ph[s]);
            const float c = __cosf(th), sn = __sinf(th);
            nre[s] = 0.7f * a[s] * c  + f * (c * SA[s] + sn * SB[s]);
            nim[s] = 0.7f * a[s] * sn + f * (c * SB[s] + sn * SC[s]);
        }

        // morph = new * conj(src) / |new|
        const size_t soff = (mrow + midx) * (size_t)D_;
        ld8(a, amp0 + soff, lane); ld8(ph, phase0 + soff, lane); ld8(pw, pv + soff, lane);
        #pragma unroll
        for (int s = 0; s < 8; ++s) {
            const float th = fmaf(0.1f, pw[s], ph[s]);
            const float c = __cosf(th), sn = __sinf(th);
            const float sre = a[s] * c, sim = a[s] * sn;
            const float inv = __builtin_amdgcn_rcpf(sqrtf(nre[s]*nre[s] + nim[s]*nim[s]));
            const float mre = (nre[s] * sre + nim[s] * sim) * inv;
            const float mim = (nim[s] * sre - nre[s] * sim) * inv;
            nre[s] = fmaf(0.02f, mre, nre[s]);
            nim[s] = fmaf(0.02f, mim, nim[s]);
        }

        const float wf = 1.f + 0.02f * __sinf(t + 2.f * PI_ * (float)i / (float)N_);
        const float scale_i = 0.1f / (1.f + 0.1f * (float)i);

        float ampn[8], rm = 0.f;
        #pragma unroll
        for (int s = 0; s < 8; ++s) {
            nre[s] *= wf; nim[s] *= wf;
            ampn[s] = sqrtf(nre[s]*nre[s] + nim[s]*nim[s]);
            rm = fmaxf(rm, ampn[s]);
        }
        #pragma unroll
        for (int off = 1; off < 64; off <<= 1) rm = fmaxf(rm, __shfl_xor(rm, off));
        const float rinv = __builtin_amdgcn_rcpf(rm + 1e-8f);

        #pragma unroll
        for (int s = 0; s < 8; ++s) {
            const float anorm = ampn[s] * rinv;
            const float iamp  = __builtin_amdgcn_rcpf(ampn[s]);
            const float ure = nre[s] * iamp, uim = nim[s] * iamp;
            const float d  = pp[s] * scale_i;           // |d| <= 0.0314
            const float d2 = d * d;
            const float cd = 1.f - 0.5f * d2;           // err < 4e-8
            const float sd = d * (1.f - 0.16666667f * d2);
            sA[s]  += anorm;
            sZr[s] += ure * cd - uim * sd;
            sZi[s] += ure * sd + uim * cd;
        }
    }

    #pragma unroll
    for (int s = 0; s < 8; ++s) {
        atomicAdd(&accA[j0 + s],  sA[s]);
        atomicAdd(&accZr[j0 + s], sZr[s]);
        atomicAdd(&accZi[j0 + s], sZi[s]);
    }
    __syncthreads();
    const int j = threadIdx.x;
    const size_t pidx = ((size_t)(m * 64 + g)) * D_ + j;
    pA[pidx]  = accA[j];
    pZr[pidx] = accZr[j];
    pZi[pidx] = accZi[j];
}

__global__ void reduce_kernel(const float* __restrict__ pA,
                              const float* __restrict__ pZr,
                              const float* __restrict__ pZi,
                              float* __restrict__ micro_out,
                              float* __restrict__ coh) {
    const int m = blockIdx.x, j = threadIdx.x;
    float sa = 0.f, zr = 0.f, zi = 0.f;
    for (int g = 0; g < 64; ++g) {
        const size_t idx = ((size_t)m * 64 + g) * D_ + j;
        sa += pA[idx]; zr += pZr[idx]; zi += pZi[idx];
    }
    micro_out[m * D_ + j] = sa * (1.f / (float)N_);
    const float mag = sqrtf(zr * zr + zi * zi) * (1.f / (float)N_);
    __shared__ float red[D_];
    red[j] = mag;
    __syncthreads();
    for (int s = D_/2; s > 0; s >>= 1) {
        if (j < s) red[j] += red[j + s];
        __syncthreads();
    }
    if (j == 0) coh[m] = red[0] / (float)D_;
}

// fused GRU: gates + nonlinearity -> h.  128 blocks x 256 thr, wave = output dim d.
__global__ __launch_bounds__(256) void macro_kernel(
    const float* __restrict__ mo, const float* __restrict__ h0,
    const float* __restrict__ w_ih, const float* __restrict__ b_ih,
    const float* __restrict__ w_hh, const float* __restrict__ b_hh,
    float* __restrict__ h)
{
    __shared__ float vx[M_ * H_], vh[M_ * H_];
    for (int idx = threadIdx.x; idx < M_ * H_; idx += 256) { vx[idx] = mo[idx]; vh[idx] = h0[idx]; }
    __syncthreads();
    const int wid = threadIdx.x >> 6, lane = threadIdx.x & 63;
    const int d = (blockIdx.x << 2) + wid;   // 0..511
    float wr[6][8];
    #pragma unroll
    for (int rr = 0; rr < 3; ++rr) {
        const size_t row = (size_t)(d + rr * H_) * H_;
        #pragma unroll
        for (int kk = 0; kk < 8; ++kk) {
            wr[rr][kk]     = w_ih[row + kk * 64 + lane];
            wr[rr + 3][kk] = w_hh[row + kk * 64 + lane];
        }
    }
    const float br = b_ih[d], bz = b_ih[d + H_], bn = b_ih[d + 2 * H_];
    const float dr = b_hh[d], dz = b_hh[d + H_], dn = b_hh[d + 2 * H_];
    for (int m = 0; m < M_; ++m) {
        float acc[6] = {0.f, 0.f, 0.f, 0.f, 0.f, 0.f};
        #pragma unroll
        for (int kk = 0; kk < 8; ++kk) {
            const float xm = vx[m * H_ + kk * 64 + lane];
            const float hm = vh[m * H_ + kk * 64 + lane];
            acc[0] = fmaf(wr[0][kk], xm, acc[0]);
            acc[1] = fmaf(wr[1][kk], xm, acc[1]);
            acc[2] = fmaf(wr[2][kk], xm, acc[2]);
            acc[3] = fmaf(wr[3][kk], hm, acc[3]);
            acc[4] = fmaf(wr[4][kk], hm, acc[4]);
            acc[5] = fmaf(wr[5][kk], hm, acc[5]);
        }
        #pragma unroll
        for (int off = 32; off; off >>= 1)
            #pragma unroll
            for (int q = 0; q < 6; ++q) acc[q] += __shfl_down(acc[q], off);
        if (lane == 0) {
            const float r  = 1.f / (1.f + expf(-(acc[0] + br + acc[3] + dr)));
            const float z  = 1.f / (1.f + expf(-(acc[1] + bz + acc[4] + dz)));
            const float ng = tanhf(acc[2] + bn + r * (acc[5] + dn));
            h[m * H_ + d] = (1.f - z) * ng + z * vh[m * H_ + d];
        }
    }
}

// 384 blocks * 256 threads, wave=row over {wq,wk,wv} x 512 rows
__global__ void qkv_kernel(const float* __restrict__ h,
                           const float* __restrict__ wq, const float* __restrict__ bq,
                           const float* __restrict__ wk, const float* __restrict__ bk,
                           const float* __restrict__ wv, const float* __restrict__ bv,
                           float* __restrict__ Q, float* __restrict__ Kk, float* __restrict__ V) {
    __shared__ float hv[M_ * H_];
    for (int idx = threadIdx.x; idx < M_ * H_; idx += blockDim.x) hv[idx] = h[idx];
    __syncthreads();
    const int gr = (blockIdx.x << 2) + (threadIdx.x >> 6);  // 0..1535
    const int lane = threadIdx.x & 63;
    const int which = gr / H_, r = gr % H_;
    const float* W = (which == 0) ? wq : ((which == 1) ? wk : wv);
    const float* B = (which == 0) ? bq : ((which == 1) ? bk : bv);
    float* O       = (which == 0) ? Q  : ((which == 1) ? Kk : V);
    float wvv[8];
    #pragma unroll
    for (int kk = 0; kk < 8; ++kk) wvv[kk] = W[(size_t)r * H_ + kk * 64 + lane];
    for (int m = 0; m < M_; ++m) {
        float acc = 0.f;
        #pragma unroll
        for (int kk = 0; kk < 8; ++kk) acc = fmaf(wvv[kk], hv[m * H_ + kk * 64 + lane], acc);
        for (int off = 32; off; off >>= 1) acc += __shfl_down(acc, off);
        if (lane == 0) O[m * H_ + r] = acc + B[r];
    }
}

// fused: attention (-> attended) + faction tension (-> out[512]). one block, 512 thr.
__global__ void attn_faction_kernel(const float* __restrict__ Q, const float* __restrict__ Kk,
                                    const float* __restrict__ V, const float* __restrict__ coh,
                                    const float* __restrict__ h, const int* __restrict__ step_p,
                                    float* __restrict__ attended, float* __restrict__ out_tension) {
    const int tid = threadIdx.x;
    // ---- faction/tension (uses h only) ----
    {
        const int j = tid;
        const int step = *step_p;
        float h2[M_];
        #pragma unroll
        for (int ff = 0; ff < 4; ++ff) {
            const float a = h[(2*ff) * H_ + j], b = h[(2*ff+1) * H_ + j];
            const float mn = 0.5f * (a + b);
            h2[2*ff]   = 0.85f * a + 0.15f * mn;
            h2[2*ff+1] = 0.85f * b + 0.15f * mn;
        }
        if (step > 5) {
            float go = 0.f;
            #pragma unroll
            for (int m = 0; m < M_; ++m) go += h2[m];
            go *= (1.f / (float)M_);
            #pragma unroll
            for (int ff = 0; ff < 4; ++ff) h2[2*ff] = 0.85f * h2[2*ff] + 0.15f * go; // fs=2 -> dc=1
        }
        float sum = 0.f, sq = 0.f;
        #pragma unroll
        for (int m = 0; m < M_; ++m) { sum += h2[m]; sq = fmaf(h2[m], h2[m], sq); }
        __shared__ float rs[D_], rq[D_];
        rs[j] = sum; rq[j] = sq;
        __syncthreads();
        for (int s = D_/2; s > 0; s >>= 1) {
            if (j < s) { rs[j] += rs[j + s]; rq[j] += rq[j + s]; }
            __syncthreads();
        }
        if (j == 0) {
            const float Nt = (float)(M_ * H_);
            const float mean = rs[0] / Nt;
            out_tension[0] = (rq[0] - Nt * mean * mean) / (Nt - 1.f);
        }
        __syncthreads();
    }
    // ---- attention ----
    __shared__ float sc[M_][M_];
    __shared__ float colw[M_];
    const int a = tid >> 6, lane = tid & 63;
    for (int b = 0; b < M_; ++b) {
        float acc = 0.f;
        #pragma unroll
        for (int kk = 0; kk < 8; ++kk) acc = fmaf(Q[a * H_ + kk * 64 + lane], Kk[b * H_ + kk * 64 + lane], acc);
        for (int off = 32; off; off >>= 1) acc += __shfl_down(acc, off);
        if (lane == 0) sc[a][b] = acc * rsqrtf((float)H_) * (0.5f + 0.5f * coh[a] * coh[b]);
    }
    __syncthreads();
    if (tid < M_) {
        float mx = -1e30f;
        for (int b = 0; b < M_; ++b) mx = fmaxf(mx, sc[tid][b]);
        float e[M_], smm = 0.f;
        for (int b = 0; b < M_; ++b) { e[b] = expf(sc[tid][b] - mx); smm += e[b]; }
        for (int b = 0; b < M_; ++b) sc[tid][b] = e[b] / smm;
    }
    __syncthreads();
    if (tid < M_) {
        float sum = 0.f;
        for (int a2 = 0; a2 < M_; ++a2) sum += sc[a2][tid];
        colw[tid] = sum * (1.f / (float)M_);
    }
    __syncthreads();
    float acc = 0.f;
    #pragma unroll
    for (int b = 0; b < M_; ++b) acc = fmaf(colw[b], V[b * H_ + tid], acc);
    attended[tid] = acc;
}

// 128 blocks * 256 threads, wave=output row
__global__ void pred_kernel(const float* __restrict__ attended,
                            const float* __restrict__ out_w, const float* __restrict__ out_b,
                            float* __restrict__ pred) {
    __shared__ float av[H_];
    for (int idx = threadIdx.x; idx < H_; idx += blockDim.x) av[idx] = attended[idx];
    __syncthreads();
    const int p = (blockIdx.x << 2) + (threadIdx.x >> 6);
    const int lane = threadIdx.x & 63;
    float acc = 0.f;
    #pragma unroll
    for (int kk = 0; kk < 8; ++kk) acc = fmaf(av[kk * 64 + lane], out_w[(size_t)p * H_ + kk * 64 + lane], acc);
    for (int off = 32; off; off >>= 1) acc += __shfl_down(acc, off);
    if (lane == 0) pred[p] = acc + out_b[p];
}

// ---------------- launcher ----------------

extern "C" void kernel_launch(void* const* d_in, const int* in_sizes, int n_in,
                              void* d_out, int out_size, void* d_ws, size_t ws_size,
                              hipStream_t stream) {
    const float* x      = (const float*)d_in[0];
    const int*   step   = (const int*)  d_in[1];
    const float* amp0   = (const float*)d_in[2];
    const float* phase0 = (const float*)d_in[3];
    const float* pvel   = (const float*)d_in[4];
    const int*   nbr_i  = (const int*)  d_in[5];
    const float* nbr_m  = (const float*)d_in[6];
    const float* h0     = (const float*)d_in[7];
    const float* w_ih   = (const float*)d_in[8];
    const float* b_ih   = (const float*)d_in[9];
    const float* w_hh   = (const float*)d_in[10];
    const float* b_hh   = (const float*)d_in[11];
    const float* wq     = (const float*)d_in[12];
    const float* bq     = (const float*)d_in[13];
    const float* wk     = (const float*)d_in[14];
    const float* bk     = (const float*)d_in[15];
    const float* wv     = (const float*)d_in[16];
    const float* bv     = (const float*)d_in[17];
    const float* out_w  = (const float*)d_in[18];
    const float* out_b  = (const float*)d_in[19];
    float* out = (float*)d_out;

    const int K = in_sizes[5] / N_;   // neighbor pad width (11)

    float* ws   = (float*)d_ws;
    float* wABS = ws + OFF_ABS;
    float* wSIG = ws + OFF_SIG;
    float* wPA  = ws + OFF_PA;
    float* wPZR = ws + OFF_PZR;
    float* wPZI = ws + OFF_PZI;
    float* wMO  = ws + OFF_MO;
    float* wCOH = ws + OFF_COH;
    float* wH   = ws + OFF_H;
    float* wQ   = ws + OFF_Q;
    float* wK   = ws + OFF_K;
    float* wV   = ws + OFF_V;
    float* wATT = ws + OFF_ATT;

    prep_kernel<<<M_ * N_ + 1, 64, 0, stream>>>(amp0, x, wABS, wSIG);
    micro_kernel<<<512, 512, 0, stream>>>(amp0, phase0, pvel, x, wSIG, nbr_i, nbr_m, step,
                                          wABS, wPA, wPZR, wPZI, K);
    reduce_kernel<<<M_, D_, 0, stream>>>(wPA, wPZR, wPZI, wMO, wCOH);
    macro_kernel<<<128, 256, 0, stream>>>(wMO, h0, w_ih, b_ih, w_hh, b_hh, wH);
    qkv_kernel<<<384, 256, 0, stream>>>(wH, wq, bq, wk, bk, wv, bv, wQ, wK, wV);
    attn_faction_kernel<<<1, 512, 0, stream>>>(wQ, wK, wV, wCOH, wH, step, wATT, out + 512);
    pred_kernel<<<128, 256, 0, stream>>>(wATT, out_w, out_b, out);
}